// Round 2
// baseline (226.376 us; speedup 1.0000x reference)
//
#include <hip/hip_runtime.h>
#include <math.h>

#define B 64
#define C 100
#define K 5
#define N (B*C*K)   // 32000

#define ALPHA 0.7f
#define L1L2_SCALE 0.00025f

// acc layout (floats, in d_ws after t and s):
// 0: sum over temps of 0.7*T^2 * sum_{b,c} p*(logp-logq)   (divide by B*C later)
// 1: sum_b log_p_s[b, target[b]]                            (ce = -acc1/B)
// 2: tt   3: ss   4: ts
// 5: sum G^2   6: sum H^2   7: L1 sum

__device__ __forceinline__ float waveReduceSum(float v) {
    #pragma unroll
    for (int off = 32; off > 0; off >>= 1)
        v += __shfl_xor(v, off, 64);
    return v;
}
__device__ __forceinline__ float waveReduceMax(float v) {
    #pragma unroll
    for (int off = 32; off > 0; off >>= 1)
        v = fmaxf(v, __shfl_xor(v, off, 64));
    return v;
}

// One wave per (k, b) row: compute teacher/student softmax at temp k+1,
// write cubes (layout t[k][b][c]), accumulate KL, CE (k==0), tt/ss/ts.
__global__ void softmax_kd_kernel(const float* __restrict__ ls,
                                  const float* __restrict__ lt,
                                  const int* __restrict__ target,
                                  float* __restrict__ t,
                                  float* __restrict__ s,
                                  float* __restrict__ acc) {
    int blk = blockIdx.x;       // 0..K*B-1
    int k = blk / B;
    int b = blk % B;
    int tid = threadIdx.x;      // 0..63
    float T = (float)(k + 1);
    float invT = 1.0f / T;

    const float* lsrow = ls + b * C;
    const float* ltrow = lt + b * C;

    int c0 = tid, c1 = tid + 64;
    bool h1 = (c1 < C);

    float as0 = lsrow[c0] * invT;
    float at0 = ltrow[c0] * invT;
    float as1 = h1 ? lsrow[c1] * invT : -INFINITY;
    float at1 = h1 ? ltrow[c1] * invT : -INFINITY;

    float ms = waveReduceMax(fmaxf(as0, as1));
    float mt = waveReduceMax(fmaxf(at0, at1));

    float es0 = expf(as0 - ms);
    float es1 = h1 ? expf(as1 - ms) : 0.0f;
    float et0 = expf(at0 - mt);
    float et1 = h1 ? expf(at1 - mt) : 0.0f;

    float Zs = waveReduceSum(es0 + es1);
    float Zt = waveReduceSum(et0 + et1);
    float logZs = logf(Zs), logZt = logf(Zt);
    float invZs = 1.0f / Zs, invZt = 1.0f / Zt;

    float q0 = es0 * invZs, q1 = es1 * invZs;   // student probs
    float p0 = et0 * invZt, p1 = et1 * invZt;   // teacher probs

    float lq0 = as0 - ms - logZs;
    float lp0 = at0 - mt - logZt;
    float lq1 = as1 - ms - logZs;   // -inf when !h1, guarded below
    float lp1 = at1 - mt - logZt;

    float* trow = t + (k * B + b) * C;
    float* srow = s + (k * B + b) * C;
    trow[c0] = p0;  srow[c0] = q0;
    if (h1) { trow[c1] = p1; srow[c1] = q1; }

    float kl_part = p0 * (lp0 - lq0) + (h1 ? p1 * (lp1 - lq1) : 0.0f);
    float tt_part = p0 * p0 + p1 * p1;
    float ss_part = q0 * q0 + q1 * q1;
    float ts_part = p0 * q0 + p1 * q1;

    float klr = waveReduceSum(kl_part);
    float ttr = waveReduceSum(tt_part);
    float ssr = waveReduceSum(ss_part);
    float tsr = waveReduceSum(ts_part);

    float cer = 0.0f;
    if (k == 0) {
        int tg = target[b];
        float cl = (c0 == tg) ? lq0 : ((h1 && c1 == tg) ? lq1 : 0.0f);
        cer = waveReduceSum(cl);
    }

    if (tid == 0) {
        atomicAdd(&acc[0], klr * (ALPHA * T * T));
        atomicAdd(&acc[2], ttr);
        atomicAdd(&acc[3], ssr);
        atomicAdd(&acc[4], tsr);
        if (k == 0) atomicAdd(&acc[1], cer);
    }
}

// G[k][i][j] = sum_c T_k[i][c]*T_k[j][c] - S_k[i][c]*S_k[j][c]; accumulate sum G^2.
// One block per (k,i), 64 threads = j.
__global__ void gram_b_kernel(const float* __restrict__ t,
                              const float* __restrict__ s,
                              float* __restrict__ acc) {
    int blk = blockIdx.x;       // k*B + i
    int k = blk / B, i = blk % B;
    int j = threadIdx.x;        // 0..63
    const float* Ti = t + (k * B + i) * C;
    const float* Si = s + (k * B + i) * C;
    const float* Tj = t + (k * B + j) * C;
    const float* Sj = s + (k * B + j) * C;
    float gt = 0.0f, gs = 0.0f;
    for (int c = 0; c < C; c++) {
        gt = fmaf(Ti[c], Tj[c], gt);
        gs = fmaf(Si[c], Sj[c], gs);
    }
    float g = gt - gs;
    float r = waveReduceSum(g * g);
    if (j == 0) atomicAdd(&acc[5], r);
}

// H[k][i][j] = sum_b T_k[b][i]*T_k[b][j] - S_k[b][i]*S_k[b][j]; accumulate sum H^2.
// One block per (k,i) with i in [0,C), 128 threads = j (active j<C).
__global__ void gram_c_kernel(const float* __restrict__ t,
                              const float* __restrict__ s,
                              float* __restrict__ acc) {
    int blk = blockIdx.x;       // k*C + i
    int k = blk / C, i = blk % C;
    int j = threadIdx.x;        // 0..127
    __shared__ float red[2];
    float h2 = 0.0f;
    if (j < C) {
        const float* Tk = t + k * B * C;
        const float* Sk = s + k * B * C;
        float ht = 0.0f, hs = 0.0f;
        for (int b = 0; b < B; b++) {
            ht = fmaf(Tk[b * C + i], Tk[b * C + j], ht);
            hs = fmaf(Sk[b * C + i], Sk[b * C + j], hs);
        }
        float h = ht - hs;
        h2 = h * h;
    }
    float r = waveReduceSum(h2);
    int wid = j >> 6;
    if ((j & 63) == 0) red[wid] = r;
    __syncthreads();
    if (j == 0) atomicAdd(&acc[6], red[0] + red[1]);
}

// Brute-force L1 over the virtual N x N outer product.
// Grid: (32 a-tiles of 1024) x (16 b-chunks of 2000). 256 threads, 4 a's each.
#define APT 4
#define L1BLK 256
#define ATILE (APT * L1BLK)   // 1024
#define BCHUNK 2000
#define NBTILES 16
#define NATILES ((N + ATILE - 1) / ATILE)   // 32

__global__ void l1_kernel(const float* __restrict__ t,
                          const float* __restrict__ s,
                          float* __restrict__ acc) {
    __shared__ float2 tile[BCHUNK];
    __shared__ float red[L1BLK / 64];
    int tid = threadIdx.x;
    int ab = blockIdx.x;   // a tile
    int bb = blockIdx.y;   // b chunk

    float ta[APT], sa[APT];
    int abase = ab * ATILE;
    #pragma unroll
    for (int u = 0; u < APT; u++) {
        int a = abase + u * L1BLK + tid;
        bool ok = (a < N);
        ta[u] = ok ? t[a] : 0.0f;
        sa[u] = ok ? s[a] : 0.0f;
    }
    int bbase = bb * BCHUNK;
    for (int idx = tid; idx < BCHUNK; idx += L1BLK) {
        tile[idx] = make_float2(t[bbase + idx], s[bbase + idx]);
    }
    __syncthreads();

    float accu[APT] = {0.0f, 0.0f, 0.0f, 0.0f};
    #pragma unroll 4
    for (int bi = 0; bi < BCHUNK; bi++) {
        float2 v = tile[bi];
        #pragma unroll
        for (int u = 0; u < APT; u++) {
            accu[u] += fabsf(ta[u] * v.x - sa[u] * v.y);
        }
    }
    float tot = (accu[0] + accu[1]) + (accu[2] + accu[3]);
    float r = waveReduceSum(tot);
    int wid = tid >> 6;
    if ((tid & 63) == 0) red[wid] = r;
    __syncthreads();
    if (tid == 0) atomicAdd(&acc[7], (red[0] + red[1]) + (red[2] + red[3]));
}

__global__ void finalize_kernel(const float* __restrict__ acc,
                                float* __restrict__ out) {
    float kl = acc[0] / (float)(B * C);
    float ce = -acc[1] / (float)B;
    float kd = kl + (float)(K) * (1.0f - ALPHA) * ce;
    float tt = acc[2], ss = acc[3], ts = acc[4];
    float l2 = L1L2_SCALE * (tt * tt - 2.0f * ts * ts + ss * ss);
    float l1 = L1L2_SCALE * acc[7];
    float sub = acc[5] + acc[6];
    out[0] = kd + l1 + l2 + sub;
}

extern "C" void kernel_launch(void* const* d_in, const int* in_sizes, int n_in,
                              void* d_out, int out_size, void* d_ws, size_t ws_size,
                              hipStream_t stream) {
    const float* ls = (const float*)d_in[0];
    const float* lt = (const float*)d_in[1];
    const int* tg = (const int*)d_in[2];

    float* t = (float*)d_ws;
    float* s = t + N;
    float* acc = s + N;

    hipMemsetAsync(acc, 0, 8 * sizeof(float), stream);
    softmax_kd_kernel<<<K * B, 64, 0, stream>>>(ls, lt, tg, t, s, acc);
    gram_b_kernel<<<K * B, 64, 0, stream>>>(t, s, acc);
    gram_c_kernel<<<K * C, 128, 0, stream>>>(t, s, acc);
    dim3 grid(NATILES, NBTILES);
    l1_kernel<<<grid, L1BLK, 0, stream>>>(t, s, acc);
    finalize_kernel<<<1, 1, 0, stream>>>(acc, (float*)d_out);
}

// Round 3
// 177.741 us; speedup vs baseline: 1.2736x; 1.2736x over previous
//
#include <hip/hip_runtime.h>
#include <math.h>

#define B 64
#define C 100
#define K 5
#define N (B*C*K)   // 32000
#define M 4096      // L1 bucket count

#define ALPHA 0.7f
#define L1L2_SCALE 0.00025f

// acc layout (floats):
// 0: sum over temps of 0.7*T^2 * sum_{b,c} p*(logp-logq)   (divide by B*C later)
// 1: sum_b log_p_s[b, target[b]]                            (ce = -acc1/B)
// 2: tt   3: ss   4: ts
// 5: sum G^2   6: sum H^2   7: L1 sum
// 8: umin (mapped uint)   9: umax (mapped uint)

__device__ __forceinline__ float waveReduceSum(float v) {
    #pragma unroll
    for (int off = 32; off > 0; off >>= 1)
        v += __shfl_xor(v, off, 64);
    return v;
}
__device__ __forceinline__ float waveReduceMax(float v) {
    #pragma unroll
    for (int off = 32; off > 0; off >>= 1)
        v = fmaxf(v, __shfl_xor(v, off, 64));
    return v;
}
__device__ __forceinline__ float waveReduceMin(float v) {
    #pragma unroll
    for (int off = 32; off > 0; off >>= 1)
        v = fminf(v, __shfl_xor(v, off, 64));
    return v;
}

// Monotone float<->uint mapping so unsigned atomicMin/Max implement float min/max.
__device__ __forceinline__ unsigned mapf(float f) {
    unsigned b = __float_as_uint(f);
    return (b & 0x80000000u) ? ~b : (b | 0x80000000u);
}
__device__ __forceinline__ float unmapf(unsigned m) {
    unsigned b = (m & 0x80000000u) ? (m & 0x7FFFFFFFu) : ~m;
    return __uint_as_float(b);
}
__device__ __forceinline__ int binOf(float x, float umin, float invw) {
    int j = (int)((x - umin) * invw);
    return min(max(j, 0), M - 1);
}

// One wave per (k, b) row: softmaxes at temp k+1, write cubes + u = log(s)-log(t),
// accumulate KL, CE (k==0), tt/ss/ts, and u min/max (mapped-uint atomics).
__global__ void softmax_kd_kernel(const float* __restrict__ ls,
                                  const float* __restrict__ lt,
                                  const int* __restrict__ target,
                                  float* __restrict__ t,
                                  float* __restrict__ s,
                                  float* __restrict__ u,
                                  float* __restrict__ acc) {
    int blk = blockIdx.x;       // 0..K*B-1
    int k = blk / B;
    int b = blk % B;
    int tid = threadIdx.x;      // 0..63
    float T = (float)(k + 1);
    float invT = 1.0f / T;

    const float* lsrow = ls + b * C;
    const float* ltrow = lt + b * C;

    int c0 = tid, c1 = tid + 64;
    bool h1 = (c1 < C);

    float as0 = lsrow[c0] * invT;
    float at0 = ltrow[c0] * invT;
    float as1 = h1 ? lsrow[c1] * invT : -INFINITY;
    float at1 = h1 ? ltrow[c1] * invT : -INFINITY;

    float ms = waveReduceMax(fmaxf(as0, as1));
    float mt = waveReduceMax(fmaxf(at0, at1));

    float es0 = expf(as0 - ms);
    float es1 = h1 ? expf(as1 - ms) : 0.0f;
    float et0 = expf(at0 - mt);
    float et1 = h1 ? expf(at1 - mt) : 0.0f;

    float Zs = waveReduceSum(es0 + es1);
    float Zt = waveReduceSum(et0 + et1);
    float logZs = logf(Zs), logZt = logf(Zt);
    float invZs = 1.0f / Zs, invZt = 1.0f / Zt;

    float q0 = es0 * invZs, q1 = es1 * invZs;   // student probs
    float p0 = et0 * invZt, p1 = et1 * invZt;   // teacher probs

    float lq0 = as0 - ms - logZs;
    float lp0 = at0 - mt - logZt;
    float lq1 = as1 - ms - logZs;   // -inf when !h1, guarded below
    float lp1 = at1 - mt - logZt;

    int rbase = (k * B + b) * C;
    float u0 = lq0 - lp0;
    t[rbase + c0] = p0;  s[rbase + c0] = q0;  u[rbase + c0] = u0;
    float u1 = 0.0f;
    if (h1) {
        u1 = lq1 - lp1;
        t[rbase + c1] = p1; s[rbase + c1] = q1; u[rbase + c1] = u1;
    }

    float umn = waveReduceMin(fminf(u0, h1 ? u1 :  INFINITY));
    float umx = waveReduceMax(fmaxf(u0, h1 ? u1 : -INFINITY));

    float kl_part = p0 * (lp0 - lq0) + (h1 ? p1 * (lp1 - lq1) : 0.0f);
    float tt_part = p0 * p0 + p1 * p1;
    float ss_part = q0 * q0 + q1 * q1;
    float ts_part = p0 * q0 + p1 * q1;

    float klr = waveReduceSum(kl_part);
    float ttr = waveReduceSum(tt_part);
    float ssr = waveReduceSum(ss_part);
    float tsr = waveReduceSum(ts_part);

    float cer = 0.0f;
    if (k == 0) {
        int tg = target[b];
        float cl = (c0 == tg) ? lq0 : ((h1 && c1 == tg) ? lq1 : 0.0f);
        cer = waveReduceSum(cl);
    }

    if (tid == 0) {
        atomicAdd(&acc[0], klr * (ALPHA * T * T));
        atomicAdd(&acc[2], ttr);
        atomicAdd(&acc[3], ssr);
        atomicAdd(&acc[4], tsr);
        if (k == 0) atomicAdd(&acc[1], cer);
        unsigned* au = (unsigned*)acc;
        atomicMin(&au[8], mapf(umn));
        atomicMax(&au[9], mapf(umx));
    }
}

// G[k][i][j] = sum_c T_k[i][c]*T_k[j][c] - S_k[i][c]*S_k[j][c]; accumulate sum G^2.
__global__ void gram_b_kernel(const float* __restrict__ t,
                              const float* __restrict__ s,
                              float* __restrict__ acc) {
    int blk = blockIdx.x;       // k*B + i
    int k = blk / B, i = blk % B;
    int j = threadIdx.x;        // 0..63
    const float* Ti = t + (k * B + i) * C;
    const float* Si = s + (k * B + i) * C;
    const float* Tj = t + (k * B + j) * C;
    const float* Sj = s + (k * B + j) * C;
    float gt = 0.0f, gs = 0.0f;
    for (int c = 0; c < C; c++) {
        gt = fmaf(Ti[c], Tj[c], gt);
        gs = fmaf(Si[c], Sj[c], gs);
    }
    float g = gt - gs;
    float r = waveReduceSum(g * g);
    if (j == 0) atomicAdd(&acc[5], r);
}

// H[k][i][j] = sum_b T_k[b][i]*T_k[b][j] - S_k[b][i]*S_k[b][j]; accumulate sum H^2.
__global__ void gram_c_kernel(const float* __restrict__ t,
                              const float* __restrict__ s,
                              float* __restrict__ acc) {
    int blk = blockIdx.x;       // k*C + i
    int k = blk / C, i = blk % C;
    int j = threadIdx.x;        // 0..127
    __shared__ float red[2];
    float h2 = 0.0f;
    if (j < C) {
        const float* Tk = t + k * B * C;
        const float* Sk = s + k * B * C;
        float ht = 0.0f, hs = 0.0f;
        for (int b = 0; b < B; b++) {
            ht = fmaf(Tk[b * C + i], Tk[b * C + j], ht);
            hs = fmaf(Sk[b * C + i], Sk[b * C + j], hs);
        }
        float h = ht - hs;
        h2 = h * h;
    }
    float r = waveReduceSum(h2);
    int wid = j >> 6;
    if ((j & 63) == 0) red[wid] = r;
    __syncthreads();
    if (j == 0) atomicAdd(&acc[6], red[0] + red[1]);
}

// ---- L1 closed form via bucket sort over u ----
__global__ void hist_kernel(const float* __restrict__ u,
                            const float* __restrict__ t,
                            const float* __restrict__ s,
                            const float* __restrict__ acc,
                            int* __restrict__ binCnt,
                            float* __restrict__ binT,
                            float* __restrict__ binS) {
    int i = blockIdx.x * blockDim.x + threadIdx.x;
    if (i >= N) return;
    const unsigned* au = (const unsigned*)acc;
    float umin = unmapf(au[8]);
    float umax = unmapf(au[9]);
    float invw = (float)M / fmaxf(umax - umin, 1e-30f);
    int j = binOf(u[i], umin, invw);
    atomicAdd(&binCnt[j], 1);
    atomicAdd(&binT[j], t[i]);
    atomicAdd(&binS[j], s[i]);
}

#define SCAN_T 256
#define PER_T (M / SCAN_T)   // 16

// Single-block exclusive scan of counts / binT / binS -> binStart, cumT, cumS, cursor.
__global__ void scan_kernel(const int* __restrict__ binCnt,
                            const float* __restrict__ binT,
                            const float* __restrict__ binS,
                            int* __restrict__ binStart,
                            float* __restrict__ cumT,
                            float* __restrict__ cumS,
                            int* __restrict__ cursor) {
    __shared__ int lc[SCAN_T];
    __shared__ float ltt[SCAN_T], lss[SCAN_T];
    int r = threadIdx.x;
    int base = r * PER_T;
    int cl[PER_T]; float tl[PER_T], sl[PER_T];
    int cp = 0; float tp = 0.f, sp = 0.f;
    #pragma unroll
    for (int e = 0; e < PER_T; e++) {
        cp += binCnt[base + e]; cl[e] = cp;
        tp += binT[base + e];   tl[e] = tp;
        sp += binS[base + e];   sl[e] = sp;
    }
    lc[r] = cp; ltt[r] = tp; lss[r] = sp;
    __syncthreads();
    for (int off = 1; off < SCAN_T; off <<= 1) {
        int cv = 0; float tv = 0.f, sv = 0.f;
        if (r >= off) { cv = lc[r - off]; tv = ltt[r - off]; sv = lss[r - off]; }
        __syncthreads();
        lc[r] += cv; ltt[r] += tv; lss[r] += sv;
        __syncthreads();
    }
    int   excC = lc[r]  - cp;
    float excT = ltt[r] - tp;
    float excS = lss[r] - sp;
    #pragma unroll
    for (int e = 0; e < PER_T; e++) {
        int bs = excC + (e ? cl[e-1] : 0);
        binStart[base + e] = bs;
        cursor[base + e]   = bs;
        cumT[base + e] = excT + (e ? tl[e-1] : 0.f);
        cumS[base + e] = excS + (e ? sl[e-1] : 0.f);
    }
    if (r == SCAN_T - 1) {
        binStart[M] = lc[r];
        cumT[M] = ltt[r];
        cumS[M] = lss[r];
    }
}

__global__ void scatter_kernel(const float* __restrict__ u,
                               const float* __restrict__ t,
                               const float* __restrict__ s,
                               const float* __restrict__ acc,
                               int* __restrict__ cursor,
                               float4* __restrict__ pack) {
    int i = blockIdx.x * blockDim.x + threadIdx.x;
    if (i >= N) return;
    const unsigned* au = (const unsigned*)acc;
    float umin = unmapf(au[8]);
    float umax = unmapf(au[9]);
    float invw = (float)M / fmaxf(umax - umin, 1e-30f);
    float x = u[i];
    int j = binOf(x, umin, invw);
    int pos = atomicAdd(&cursor[j], 1);
    pack[pos] = make_float4(x, t[i], s[i], 0.f);
}

// Per-a closed form: row_a = t_a*(2*T_le - T_tot) + s_a*(S_tot - 2*S_le),
// T_le = sum of t_b with u_b <= -u_a (prefix bins + exact partial-bin scan).
__global__ void l1_closed_kernel(const float* __restrict__ u,
                                 const float* __restrict__ t,
                                 const float* __restrict__ s,
                                 const float* __restrict__ acc_in,
                                 const int* __restrict__ binStart,
                                 const float* __restrict__ cumT,
                                 const float* __restrict__ cumS,
                                 const float4* __restrict__ pack,
                                 float* __restrict__ acc) {
    __shared__ float red[4];
    int a = blockIdx.x * blockDim.x + threadIdx.x;
    int tid = threadIdx.x;
    const unsigned* au = (const unsigned*)acc_in;
    float umin = unmapf(au[8]);
    float umax = unmapf(au[9]);
    float invw = (float)M / fmaxf(umax - umin, 1e-30f);
    float T_tot = cumT[M], S_tot = cumS[M];

    float row = 0.0f;
    if (a < N) {
        float x = -u[a];
        int j = binOf(x, umin, invw);
        float T_le = cumT[j], S_le = cumS[j];
        int p0 = binStart[j], p1 = binStart[j + 1];
        for (int p = p0; p < p1; p++) {
            float4 v = pack[p];
            if (v.x <= x) { T_le += v.y; S_le += v.z; }
        }
        row = t[a] * (2.0f * T_le - T_tot) + s[a] * (S_tot - 2.0f * S_le);
    }
    float r = waveReduceSum(row);
    int wid = tid >> 6;
    if ((tid & 63) == 0) red[wid] = r;
    __syncthreads();
    if (tid == 0) atomicAdd(&acc[7], (red[0] + red[1]) + (red[2] + red[3]));
}

__global__ void finalize_kernel(const float* __restrict__ acc,
                                float* __restrict__ out) {
    float kl = acc[0] / (float)(B * C);
    float ce = -acc[1] / (float)B;
    float kd = kl + (float)(K) * (1.0f - ALPHA) * ce;
    float tt = acc[2], ss = acc[3], ts = acc[4];
    float l2 = L1L2_SCALE * (tt * tt - 2.0f * ts * ts + ss * ss);
    float l1 = L1L2_SCALE * acc[7];
    float sub = acc[5] + acc[6];
    out[0] = kd + l1 + l2 + sub;
}

extern "C" void kernel_launch(void* const* d_in, const int* in_sizes, int n_in,
                              void* d_out, int out_size, void* d_ws, size_t ws_size,
                              hipStream_t stream) {
    const float* ls = (const float*)d_in[0];
    const float* lt = (const float*)d_in[1];
    const int* tg = (const int*)d_in[2];

    // workspace layout (all 4-byte types; pack is 16B-aligned: 3N*4 = 384000 % 16 == 0)
    float* t = (float*)d_ws;            // N
    float* s = t + N;                   // N
    float* u = s + N;                   // N
    float4* pack = (float4*)(u + N);    // N float4
    float* acc = (float*)(pack + N);    // 16
    int* binCnt = (int*)(acc + 16);     // M
    float* binT = (float*)(binCnt + M); // M
    float* binS = binT + M;             // M
    int* binStart = (int*)(binS + M);   // M+1
    float* cumT = (float*)(binStart + (M + 1)); // M+1
    float* cumS = cumT + (M + 1);       // M+1
    int* cursor = (int*)(cumS + (M + 1)); // M

    // zero acc + binCnt + binT + binS in one shot, then set umin slot to +max
    hipMemsetAsync(acc, 0, (16 + 3 * M) * sizeof(float), stream);
    hipMemsetAsync(acc + 8, 0xFF, sizeof(float), stream);  // umin (mapped) = 0xFFFFFFFF

    softmax_kd_kernel<<<K * B, 64, 0, stream>>>(ls, lt, tg, t, s, u, acc);
    gram_b_kernel<<<K * B, 64, 0, stream>>>(t, s, acc);
    gram_c_kernel<<<K * C, 128, 0, stream>>>(t, s, acc);
    hist_kernel<<<N / 256, 256, 0, stream>>>(u, t, s, acc, binCnt, binT, binS);
    scan_kernel<<<1, SCAN_T, 0, stream>>>(binCnt, binT, binS, binStart, cumT, cumS, cursor);
    scatter_kernel<<<N / 256, 256, 0, stream>>>(u, t, s, acc, cursor, pack);
    l1_closed_kernel<<<N / 256, 256, 0, stream>>>(u, t, s, acc, binStart, cumT, cumS, pack, acc);
    finalize_kernel<<<1, 1, 0, stream>>>(acc, (float*)d_out);
}

// Round 4
// 136.963 us; speedup vs baseline: 1.6528x; 1.2977x over previous
//
#include <hip/hip_runtime.h>
#include <math.h>

#define B 64
#define C 100
#define K 5
#define N (B*C*K)   // 32000
#define M 4096      // L1 bucket count (log-spaced over u)

#define ALPHA 0.7f
#define L1L2_SCALE 0.00025f

// acc layout (floats):
// 0: sum over temps of 0.7*T^2 * sum_{b,c} p*(logp-logq)   (divide by B*C later)
// 1: sum_b log_p_s[b, target[b]]                            (ce = -acc1/B)
// 2: tt   3: ss   4: ts
// 5: sum G^2   6: sum H^2   7: L1 sum

__device__ __forceinline__ float waveReduceSum(float v) {
    #pragma unroll
    for (int off = 32; off > 0; off >>= 1)
        v += __shfl_xor(v, off, 64);
    return v;
}
__device__ __forceinline__ float waveReduceMax(float v) {
    #pragma unroll
    for (int off = 32; off > 0; off >>= 1)
        v = fmaxf(v, __shfl_xor(v, off, 64));
    return v;
}

// Fixed, weakly-monotone log-spaced binning of u. Exactness of the L1 closed
// form only needs monotonicity (within-bin resolved by explicit compare);
// log spacing equalizes bin populations across the per-temperature u scales
// (T=5 packs |u|<0.2; T=1 spreads to |u|~10) -> kills atomic hot-spots.
__device__ __forceinline__ int binOf(float x) {
    float a = fabsf(x);
    float f = log2f(fmaf(a, 1024.0f, 1.0f)) * 76.0f;  // 0..2047 for a <= ~1.2e5
    int j = (int)f;
    j = min(j, 2047);
    return (x < 0.0f) ? (2047 - j) : (2048 + j);
}

// One wave per (k, b) row: softmaxes at temp k+1, write cubes + u = log(s)-log(t),
// accumulate KL, CE (k==0), tt/ss/ts, and histogram (count, t, s) per u-bin.
__global__ void softmax_kd_hist_kernel(const float* __restrict__ ls,
                                       const float* __restrict__ lt,
                                       const int* __restrict__ target,
                                       float* __restrict__ t,
                                       float* __restrict__ s,
                                       float* __restrict__ u,
                                       float* __restrict__ acc,
                                       int* __restrict__ binCnt,
                                       float* __restrict__ binT,
                                       float* __restrict__ binS) {
    int blk = blockIdx.x;       // 0..K*B-1
    int k = blk / B;
    int b = blk % B;
    int tid = threadIdx.x;      // 0..63
    float T = (float)(k + 1);
    float invT = 1.0f / T;

    const float* lsrow = ls + b * C;
    const float* ltrow = lt + b * C;

    int c0 = tid, c1 = tid + 64;
    bool h1 = (c1 < C);

    float as0 = lsrow[c0] * invT;
    float at0 = ltrow[c0] * invT;
    float as1 = h1 ? lsrow[c1] * invT : -INFINITY;
    float at1 = h1 ? ltrow[c1] * invT : -INFINITY;

    float ms = waveReduceMax(fmaxf(as0, as1));
    float mt = waveReduceMax(fmaxf(at0, at1));

    float es0 = expf(as0 - ms);
    float es1 = h1 ? expf(as1 - ms) : 0.0f;
    float et0 = expf(at0 - mt);
    float et1 = h1 ? expf(at1 - mt) : 0.0f;

    float Zs = waveReduceSum(es0 + es1);
    float Zt = waveReduceSum(et0 + et1);
    float logZs = logf(Zs), logZt = logf(Zt);
    float invZs = 1.0f / Zs, invZt = 1.0f / Zt;

    float q0 = es0 * invZs, q1 = es1 * invZs;   // student probs
    float p0 = et0 * invZt, p1 = et1 * invZt;   // teacher probs

    float lq0 = as0 - ms - logZs;
    float lp0 = at0 - mt - logZt;
    float lq1 = as1 - ms - logZs;   // -inf when !h1, guarded below
    float lp1 = at1 - mt - logZt;

    int rbase = (k * B + b) * C;
    float u0 = lq0 - lp0;
    t[rbase + c0] = p0;  s[rbase + c0] = q0;  u[rbase + c0] = u0;
    int j0 = binOf(u0);
    atomicAdd(&binCnt[j0], 1);
    atomicAdd(&binT[j0], p0);
    atomicAdd(&binS[j0], q0);
    if (h1) {
        float u1 = lq1 - lp1;
        t[rbase + c1] = p1; s[rbase + c1] = q1; u[rbase + c1] = u1;
        int j1 = binOf(u1);
        atomicAdd(&binCnt[j1], 1);
        atomicAdd(&binT[j1], p1);
        atomicAdd(&binS[j1], q1);
    }

    float kl_part = p0 * (lp0 - lq0) + (h1 ? p1 * (lp1 - lq1) : 0.0f);
    float tt_part = p0 * p0 + p1 * p1;
    float ss_part = q0 * q0 + q1 * q1;
    float ts_part = p0 * q0 + p1 * q1;

    float klr = waveReduceSum(kl_part);
    float ttr = waveReduceSum(tt_part);
    float ssr = waveReduceSum(ss_part);
    float tsr = waveReduceSum(ts_part);

    float cer = 0.0f;
    if (k == 0) {
        int tg = target[b];
        float cl = (c0 == tg) ? lq0 : ((h1 && c1 == tg) ? lq1 : 0.0f);
        cer = waveReduceSum(cl);
    }

    if (tid == 0) {
        atomicAdd(&acc[0], klr * (ALPHA * T * T));
        atomicAdd(&acc[2], ttr);
        atomicAdd(&acc[3], ssr);
        atomicAdd(&acc[4], tsr);
        if (k == 0) atomicAdd(&acc[1], cer);
    }
}

// Fused Gram losses, one dispatch, 128 threads/block.
// Blocks [0,160): G[k][i][j] = sum_c T_k[i,c]T_k[j,c] - S_k[i,c]S_k[j,c]
//   k = bx/32; each wave handles one i ((bx%32)*2 + wave), lanes = j (64).
// Blocks [160,660): H[k][i][j] = sum_b T_k[b,i]T_k[b,j] - S_k[b,i]S_k[b,j]
//   bx-160 = k*100 + i; threads = j (j<100 active).
__global__ void gram_kernel(const float* __restrict__ t,
                            const float* __restrict__ s,
                            float* __restrict__ acc) {
    int bx = blockIdx.x;
    int tid = threadIdx.x;
    if (bx < 160) {
        int wave = tid >> 6, lane = tid & 63;
        int k = bx / 32;
        int i = (bx % 32) * 2 + wave;
        int j = lane;
        const float* Ti = t + (k * B + i) * C;
        const float* Si = s + (k * B + i) * C;
        const float* Tj = t + (k * B + j) * C;
        const float* Sj = s + (k * B + j) * C;
        float gt = 0.0f, gs = 0.0f;
        #pragma unroll 4
        for (int c = 0; c < C; c++) {
            gt = fmaf(Ti[c], Tj[c], gt);
            gs = fmaf(Si[c], Sj[c], gs);
        }
        float g = gt - gs;
        float r = waveReduceSum(g * g);
        if (lane == 0) atomicAdd(&acc[5], r);
    } else {
        int b2 = bx - 160;          // k*C + i
        int k = b2 / C, i = b2 % C;
        int j = tid;                // 0..127
        __shared__ float red[2];
        float h2 = 0.0f;
        if (j < C) {
            const float* Tk = t + k * B * C;
            const float* Sk = s + k * B * C;
            float ht = 0.0f, hs = 0.0f;
            #pragma unroll 4
            for (int b = 0; b < B; b++) {
                ht = fmaf(Tk[b * C + i], Tk[b * C + j], ht);
                hs = fmaf(Sk[b * C + i], Sk[b * C + j], hs);
            }
            float h = ht - hs;
            h2 = h * h;
        }
        float r = waveReduceSum(h2);
        int wid = j >> 6;
        if ((j & 63) == 0) red[wid] = r;
        __syncthreads();
        if (tid == 0) atomicAdd(&acc[6], red[0] + red[1]);
    }
}

#define SCAN_T 256
#define PER_T (M / SCAN_T)   // 16

// Single-block exclusive scan of counts / binT / binS -> binStart, cumT, cumS, cursor.
__global__ void scan_kernel(const int* __restrict__ binCnt,
                            const float* __restrict__ binT,
                            const float* __restrict__ binS,
                            int* __restrict__ binStart,
                            float* __restrict__ cumT,
                            float* __restrict__ cumS,
                            int* __restrict__ cursor) {
    __shared__ int lc[SCAN_T];
    __shared__ float ltt[SCAN_T], lss[SCAN_T];
    int r = threadIdx.x;
    int base = r * PER_T;
    int cl[PER_T]; float tl[PER_T], sl[PER_T];
    int cp = 0; float tp = 0.f, sp = 0.f;
    #pragma unroll
    for (int e = 0; e < PER_T; e++) {
        cp += binCnt[base + e]; cl[e] = cp;
        tp += binT[base + e];   tl[e] = tp;
        sp += binS[base + e];   sl[e] = sp;
    }
    lc[r] = cp; ltt[r] = tp; lss[r] = sp;
    __syncthreads();
    for (int off = 1; off < SCAN_T; off <<= 1) {
        int cv = 0; float tv = 0.f, sv = 0.f;
        if (r >= off) { cv = lc[r - off]; tv = ltt[r - off]; sv = lss[r - off]; }
        __syncthreads();
        lc[r] += cv; ltt[r] += tv; lss[r] += sv;
        __syncthreads();
    }
    int   excC = lc[r]  - cp;
    float excT = ltt[r] - tp;
    float excS = lss[r] - sp;
    #pragma unroll
    for (int e = 0; e < PER_T; e++) {
        int bs = excC + (e ? cl[e-1] : 0);
        binStart[base + e] = bs;
        cursor[base + e]   = bs;
        cumT[base + e] = excT + (e ? tl[e-1] : 0.f);
        cumS[base + e] = excS + (e ? sl[e-1] : 0.f);
    }
    if (r == SCAN_T - 1) {
        binStart[M] = lc[r];
        cumT[M] = ltt[r];
        cumS[M] = lss[r];
    }
}

__global__ void scatter_kernel(const float* __restrict__ u,
                               const float* __restrict__ t,
                               const float* __restrict__ s,
                               int* __restrict__ cursor,
                               float4* __restrict__ pack) {
    int i = blockIdx.x * blockDim.x + threadIdx.x;
    if (i >= N) return;
    float x = u[i];
    int j = binOf(x);
    int pos = atomicAdd(&cursor[j], 1);
    pack[pos] = make_float4(x, t[i], s[i], 0.f);
}

// Per-a closed form: row_a = t_a*(2*T_le - T_tot) + s_a*(S_tot - 2*S_le),
// T_le = sum of t_b with u_b <= -u_a (prefix bins + exact partial-bin scan).
__global__ void l1_closed_kernel(const float* __restrict__ u,
                                 const float* __restrict__ t,
                                 const float* __restrict__ s,
                                 const int* __restrict__ binStart,
                                 const float* __restrict__ cumT,
                                 const float* __restrict__ cumS,
                                 const float4* __restrict__ pack,
                                 float* __restrict__ acc) {
    __shared__ float red[4];
    int a = blockIdx.x * blockDim.x + threadIdx.x;
    int tid = threadIdx.x;
    float T_tot = cumT[M], S_tot = cumS[M];

    float row = 0.0f;
    if (a < N) {
        float x = -u[a];
        int j = binOf(x);
        float T_le = cumT[j], S_le = cumS[j];
        int p0 = binStart[j], p1 = binStart[j + 1];
        for (int p = p0; p < p1; p++) {
            float4 v = pack[p];
            if (v.x <= x) { T_le += v.y; S_le += v.z; }
        }
        row = t[a] * (2.0f * T_le - T_tot) + s[a] * (S_tot - 2.0f * S_le);
    }
    float r = waveReduceSum(row);
    int wid = tid >> 6;
    if ((tid & 63) == 0) red[wid] = r;
    __syncthreads();
    if (tid == 0) atomicAdd(&acc[7], (red[0] + red[1]) + (red[2] + red[3]));
}

__global__ void finalize_kernel(const float* __restrict__ acc,
                                float* __restrict__ out) {
    float kl = acc[0] / (float)(B * C);
    float ce = -acc[1] / (float)B;
    float kd = kl + (float)(K) * (1.0f - ALPHA) * ce;
    float tt = acc[2], ss = acc[3], ts = acc[4];
    float l2 = L1L2_SCALE * (tt * tt - 2.0f * ts * ts + ss * ss);
    float l1 = L1L2_SCALE * acc[7];
    float sub = acc[5] + acc[6];
    out[0] = kd + l1 + l2 + sub;
}

extern "C" void kernel_launch(void* const* d_in, const int* in_sizes, int n_in,
                              void* d_out, int out_size, void* d_ws, size_t ws_size,
                              hipStream_t stream) {
    const float* ls = (const float*)d_in[0];
    const float* lt = (const float*)d_in[1];
    const int* tg = (const int*)d_in[2];

    // workspace layout (pack is 16B-aligned: 3N*4 = 384000 % 16 == 0)
    float* t = (float*)d_ws;            // N
    float* s = t + N;                   // N
    float* u = s + N;                   // N
    float4* pack = (float4*)(u + N);    // N float4
    float* acc = (float*)(pack + N);    // 16
    int* binCnt = (int*)(acc + 16);     // M
    float* binT = (float*)(binCnt + M); // M
    float* binS = binT + M;             // M
    int* binStart = (int*)(binS + M);   // M+1
    float* cumT = (float*)(binStart + (M + 1)); // M+1
    float* cumS = cumT + (M + 1);       // M+1
    int* cursor = (int*)(cumS + (M + 1)); // M

    // zero acc + binCnt + binT + binS in one shot
    hipMemsetAsync(acc, 0, (16 + 3 * M) * sizeof(float), stream);

    softmax_kd_hist_kernel<<<K * B, 64, 0, stream>>>(ls, lt, tg, t, s, u, acc,
                                                     binCnt, binT, binS);
    gram_kernel<<<660, 128, 0, stream>>>(t, s, acc);
    scan_kernel<<<1, SCAN_T, 0, stream>>>(binCnt, binT, binS, binStart, cumT, cumS, cursor);
    scatter_kernel<<<N / 256, 256, 0, stream>>>(u, t, s, cursor, pack);
    l1_closed_kernel<<<N / 256, 256, 0, stream>>>(u, t, s, binStart, cumT, cumS, pack, acc);
    finalize_kernel<<<1, 1, 0, stream>>>(acc, (float*)d_out);
}